// Round 1
// baseline (130.399 us; speedup 1.0000x reference)
//
#include <hip/hip_runtime.h>

#define F 16
#define XL 128

// bands layout in d_ws: float bands[2][5][128]
//   pass 0 = row operator (x/w direction), pass 1 = column operator (y/h)
//   bands[p][d][pos] = coefficient of u[pos + d - 2] in deviation at pos.
//   Out-of-range taps stored as 0.

__device__ __forceinline__ float g1f(const float* __restrict__ w1,
                                     const float* __restrict__ w1L,
                                     const float* __restrict__ w1R,
                                     int f, int v, int wp) {
  // coefficient of u[wp] in first-order field dX[f, v]
  if (v == 0) {
    if (wp == 0) return w1L[f * 2 + 0];
    if (wp == 1) return w1L[f * 2 + 1];
    return 0.f;
  }
  if (v == XL - 1) {
    if (wp == XL - 2) return w1R[f * 2 + 0];
    if (wp == XL - 1) return w1R[f * 2 + 1];
    return 0.f;
  }
  int k = wp - (v - 1);
  return (k >= 0 && k < 3) ? w1[f * 3 + k] : 0.f;
}

__global__ __launch_bounds__(256)
void build_bands_kernel(const float* __restrict__ wX1, const float* __restrict__ wX1L,
                        const float* __restrict__ wX1R, const float* __restrict__ wY1,
                        const float* __restrict__ wY1L, const float* __restrict__ wY1R,
                        const float* __restrict__ wX2, const float* __restrict__ wX2L,
                        const float* __restrict__ wX2R, const float* __restrict__ wY2,
                        const float* __restrict__ wY2L, const float* __restrict__ wY2R,
                        const float* __restrict__ wfc, float* __restrict__ bands) {
  // fc-reduced weights (summed over output channel against wfc)
  __shared__ float r1s[2][3], r1Ls[2][2], r1Rs[2][2];
  __shared__ float qs[2][F][3], qLs[2][F][2], qRs[2][F][2];

  const int t = threadIdx.x;
  if (t < 6) {                       // first-order interior: 2 passes x 3 taps
    int p = t / 3, k = t % 3;
    const float* w1 = p ? wY1 : wX1;
    int off = p ? F : 0;
    float s = 0.f;
    for (int f = 0; f < F; ++f) s += wfc[off + f] * w1[f * 3 + k];
    r1s[p][k] = s;
  } else if (t < 10) {               // first-order left boundary
    int t2 = t - 6; int p = t2 / 2, k = t2 % 2;
    const float* w1L = p ? wY1L : wX1L;
    int off = p ? F : 0;
    float s = 0.f;
    for (int f = 0; f < F; ++f) s += wfc[off + f] * w1L[f * 2 + k];
    r1Ls[p][k] = s;
  } else if (t < 14) {               // first-order right boundary
    int t2 = t - 10; int p = t2 / 2, k = t2 % 2;
    const float* w1R = p ? wY1R : wX1R;
    int off = p ? F : 0;
    float s = 0.f;
    for (int f = 0; f < F; ++f) s += wfc[off + f] * w1R[f * 2 + k];
    r1Rs[p][k] = s;
  } else if (t < 14 + 96) {          // second-order interior: 2 x 16fi x 3
    int t2 = t - 14; int p = t2 / 48; int r = t2 % 48; int fi = r / 3, k = r % 3;
    const float* w2 = p ? wY2 : wX2;
    int off = p ? 3 * F : 2 * F;
    float s = 0.f;
    for (int fo = 0; fo < F; ++fo) s += wfc[off + fo] * w2[(fo * F + fi) * 3 + k];
    qs[p][fi][k] = s;
  } else if (t < 110 + 64) {         // second-order left boundary
    int t2 = t - 110; int p = t2 / 32; int r = t2 % 32; int fi = r / 2, k = r % 2;
    const float* w2L = p ? wY2L : wX2L;
    int off = p ? 3 * F : 2 * F;
    float s = 0.f;
    for (int fo = 0; fo < F; ++fo) s += wfc[off + fo] * w2L[(fo * F + fi) * 2 + k];
    qLs[p][fi][k] = s;
  } else if (t < 174 + 64) {         // second-order right boundary
    int t2 = t - 174; int p = t2 / 32; int r = t2 % 32; int fi = r / 2, k = r % 2;
    const float* w2R = p ? wY2R : wX2R;
    int off = p ? 3 * F : 2 * F;
    float s = 0.f;
    for (int fo = 0; fo < F; ++fo) s += wfc[off + fo] * w2R[(fo * F + fi) * 2 + k];
    qRs[p][fi][k] = s;
  }
  __syncthreads();

  int gid = blockIdx.x * 256 + t;
  if (gid >= 2 * XL * 5) return;
  const int p = gid / (XL * 5);
  const int rem = gid % (XL * 5);
  const int w = rem / 5;
  const int d = rem % 5;
  const int wp = w + d - 2;

  const float* w1  = p ? wY1  : wX1;
  const float* w1L = p ? wY1L : wX1L;
  const float* w1R = p ? wY1R : wX1R;

  float c = 0.f;
  if (wp >= 0 && wp < XL) {
    // first-order contribution
    if (w == 0) {
      if (wp == 0)       c += r1Ls[p][0];
      else if (wp == 1)  c += r1Ls[p][1];
    } else if (w == XL - 1) {
      if (wp == XL - 2)      c += r1Rs[p][0];
      else if (wp == XL - 1) c += r1Rs[p][1];
    } else {
      int k = wp - (w - 1);
      if (k >= 0 && k < 3) c += r1s[p][k];
    }
    // second-order contribution
    if (w == 0) {
      for (int vi = 0; vi < 2; ++vi)
        for (int fi = 0; fi < F; ++fi)
          c += qLs[p][fi][vi] * g1f(w1, w1L, w1R, fi, vi, wp);
    } else if (w == XL - 1) {
      for (int vi = 0; vi < 2; ++vi)
        for (int fi = 0; fi < F; ++fi)
          c += qRs[p][fi][vi] * g1f(w1, w1L, w1R, fi, XL - 2 + vi, wp);
    } else {
      for (int k2 = 0; k2 < 3; ++k2) {
        int v = w - 1 + k2;
        for (int fi = 0; fi < F; ++fi)
          c += qs[p][fi][k2] * g1f(w1, w1L, w1R, fi, v, wp);
      }
    }
  }
  bands[(p * 5 + d) * XL + w] = c;
}

// 256 blocks = 64 images x 4 strips. Each block: 64-row strip in LDS
// (32 interior rows + 16-row halos; halo 16 = 8 iters x radius 2),
// all iterations done locally (trapezoidal time tiling), in-place via
// register staging. Only the 32 valid interior rows are stored.
__global__ __launch_bounds__(256)
void fd_main_kernel(const float* __restrict__ x_in, const float* __restrict__ bands,
                    const int* __restrict__ fdp, float* __restrict__ x_out) {
  __shared__ float buf[64 * XL];   // 32 KB
  __shared__ float cbl[5 * XL];    // column band table (boundary rows only)

  const int tid = threadIdx.x;
  const int n = blockIdx.x >> 2;
  const int s = blockIdx.x & 3;
  const int g0 = (s == 0) ? 0 : (s == 1) ? 16 : (s == 2) ? 48 : 64;  // first global row in buffer
  const int l0 = (s == 0) ? 0 : (s == 3) ? 32 : 16;                  // local row of first interior row

  if (tid < XL) {
#pragma unroll
    for (int d = 0; d < 5; ++d) cbl[d * XL + tid] = bands[5 * XL + d * XL + tid];
  }

  // load strip rows [g0, g0+64)
  {
    const float4* sg4 = (const float4*)(x_in + n * (XL * XL) + g0 * XL);
    float4* b4 = (float4*)buf;
#pragma unroll
    for (int i = 0; i < 8; ++i) b4[tid + 256 * i] = sg4[tid + 256 * i];
  }

  const int w = tid & 127;
  const int half = tid >> 7;      // wave-uniform
  const int rbase = half << 5;    // rows [rbase, rbase+32)
  const int wm2 = (w >= 2) ? w - 2 : 0;
  const int wm1 = (w >= 1) ? w - 1 : 0;
  const int wp1 = (w <= 126) ? w + 1 : 127;
  const int wp2 = (w <= 125) ? w + 2 : 127;

  // per-thread row-band coefficients (vary per w; OOB taps are 0)
  const float rb0 = bands[0 * XL + w];
  const float rb1 = bands[1 * XL + w];
  const float rb2 = bands[2 * XL + w];
  const float rb3 = bands[3 * XL + w];
  const float rb4 = bands[4 * XL + w];
  // interior column-band coefficients (position-independent for rows 2..125)
  const float cbi0 = bands[5 * XL + 0 * XL + 64];
  const float cbi1 = bands[5 * XL + 1 * XL + 64];
  const float cbi2 = bands[5 * XL + 2 * XL + 64];
  const float cbi3 = bands[5 * XL + 3 * XL + 64];
  const float cbi4 = bands[5 * XL + 4 * XL + 64];

  const int fdb = fdp[0];

  __syncthreads();

  float acc[32];
  if (fdb == 0) {
#pragma unroll
    for (int j = 0; j < 32; ++j) acc[j] = buf[(rbase + j) * XL + w];
  }

  for (int t = 0; t < fdb; ++t) {
    // rolling vertical window: rows r-2 .. r+2 at column w
    float c_m2 = buf[((rbase >= 2) ? rbase - 2 : 0) * XL + w];
    float c_m1 = buf[((rbase >= 1) ? rbase - 1 : 0) * XL + w];
    float c_0  = buf[(rbase + 0) * XL + w];
    float c_p1 = buf[(rbase + 1) * XL + w];
    float c_p2 = buf[(rbase + 2) * XL + w];
#pragma unroll
    for (int j = 0; j < 32; ++j) {
      const int r = rbase + j;
      const int gh = g0 + r;
      const int ro = r * XL;
      const float hm2 = buf[ro + wm2];
      const float hm1 = buf[ro + wm1];
      const float hp1 = buf[ro + wp1];
      const float hp2 = buf[ro + wp2];
      float b0 = cbi0, b1 = cbi1, b2 = cbi2, b3 = cbi3, b4 = cbi4;
      if (gh < 2 || gh > 125) {   // wave-uniform branch, 4 rows per image
        b0 = cbl[0 * XL + gh]; b1 = cbl[1 * XL + gh]; b2 = cbl[2 * XL + gh];
        b3 = cbl[3 * XL + gh]; b4 = cbl[4 * XL + gh];
      }
      float a = c_0;                                        // identity
      a += rb0 * hm2 + rb1 * hm1 + rb2 * c_0 + rb3 * hp1 + rb4 * hp2;   // row op
      a += b0 * c_m2 + b1 * c_m1 + b2 * c_0 + b3 * c_p1 + b4 * c_p2;    // col op
      acc[j] = a;
      // roll window down one row
      c_m2 = c_m1; c_m1 = c_0; c_0 = c_p1; c_p1 = c_p2;
      const int rn = r + 3;
      c_p2 = buf[((rn <= 63) ? rn : 63) * XL + w];
    }
    if (t == fdb - 1) break;   // final values stay in acc; no write-back needed
    __syncthreads();
#pragma unroll
    for (int j = 0; j < 32; ++j) buf[(rbase + j) * XL + w] = acc[j];
    __syncthreads();
  }

  // store valid interior rows: local [l0, l0+32) -> global rows [32s, 32s+32)
#pragma unroll
  for (int j = 0; j < 32; ++j) {
    const int r = rbase + j;
    const int lr = r - l0;
    if (lr >= 0 && lr < 32) {
      x_out[n * (XL * XL) + (32 * s + lr) * XL + w] = acc[j];
    }
  }
}

extern "C" void kernel_launch(void* const* d_in, const int* in_sizes, int n_in,
                              void* d_out, int out_size, void* d_ws, size_t ws_size,
                              hipStream_t stream) {
  const float* xInput = (const float*)d_in[0];
  const float* wX1  = (const float*)d_in[1];
  const float* wX1L = (const float*)d_in[2];
  const float* wX1R = (const float*)d_in[3];
  const float* wY1  = (const float*)d_in[4];
  const float* wY1L = (const float*)d_in[5];
  const float* wY1R = (const float*)d_in[6];
  const float* wX2  = (const float*)d_in[7];
  const float* wX2L = (const float*)d_in[8];
  const float* wX2R = (const float*)d_in[9];
  const float* wY2  = (const float*)d_in[10];
  const float* wY2L = (const float*)d_in[11];
  const float* wY2R = (const float*)d_in[12];
  const float* wfc  = (const float*)d_in[13];
  const int*   fdp  = (const int*)d_in[14];

  float* bands = (float*)d_ws;           // 2*5*128 floats = 5120 B
  float* out = (float*)d_out;

  build_bands_kernel<<<5, 256, 0, stream>>>(wX1, wX1L, wX1R, wY1, wY1L, wY1R,
                                            wX2, wX2L, wX2R, wY2, wY2L, wY2R,
                                            wfc, bands);
  fd_main_kernel<<<256, 256, 0, stream>>>(xInput, bands, fdp, out);
}

// Round 2
// 110.134 us; speedup vs baseline: 1.1840x; 1.1840x over previous
//
#include <hip/hip_runtime.h>

#define F 16
#define XL 128

// bands layout in d_ws: float bands[2][5][128]
//   pass 0 = row operator (x/w direction), pass 1 = column operator (y/h)
//   bands[p][d][pos] = coefficient of u[pos + d - 2] in deviation at pos.
//   Out-of-range taps stored as 0.

__device__ __forceinline__ float g1f(const float* __restrict__ w1,
                                     const float* __restrict__ w1L,
                                     const float* __restrict__ w1R,
                                     int f, int v, int wp) {
  // coefficient of u[wp] in first-order field dX[f, v]
  if (v == 0) {
    if (wp == 0) return w1L[f * 2 + 0];
    if (wp == 1) return w1L[f * 2 + 1];
    return 0.f;
  }
  if (v == XL - 1) {
    if (wp == XL - 2) return w1R[f * 2 + 0];
    if (wp == XL - 1) return w1R[f * 2 + 1];
    return 0.f;
  }
  int k = wp - (v - 1);
  return (k >= 0 && k < 3) ? w1[f * 3 + k] : 0.f;
}

__global__ __launch_bounds__(256)
void build_bands_kernel(const float* __restrict__ wX1, const float* __restrict__ wX1L,
                        const float* __restrict__ wX1R, const float* __restrict__ wY1,
                        const float* __restrict__ wY1L, const float* __restrict__ wY1R,
                        const float* __restrict__ wX2, const float* __restrict__ wX2L,
                        const float* __restrict__ wX2R, const float* __restrict__ wY2,
                        const float* __restrict__ wY2L, const float* __restrict__ wY2R,
                        const float* __restrict__ wfc, float* __restrict__ bands) {
  // fc-reduced weights (summed over output channel against wfc)
  __shared__ float r1s[2][3], r1Ls[2][2], r1Rs[2][2];
  __shared__ float qs[2][F][3], qLs[2][F][2], qRs[2][F][2];

  const int t = threadIdx.x;
  if (t < 6) {                       // first-order interior: 2 passes x 3 taps
    int p = t / 3, k = t % 3;
    const float* w1 = p ? wY1 : wX1;
    int off = p ? F : 0;
    float s = 0.f;
    for (int f = 0; f < F; ++f) s += wfc[off + f] * w1[f * 3 + k];
    r1s[p][k] = s;
  } else if (t < 10) {               // first-order left boundary
    int t2 = t - 6; int p = t2 / 2, k = t2 % 2;
    const float* w1L = p ? wY1L : wX1L;
    int off = p ? F : 0;
    float s = 0.f;
    for (int f = 0; f < F; ++f) s += wfc[off + f] * w1L[f * 2 + k];
    r1Ls[p][k] = s;
  } else if (t < 14) {               // first-order right boundary
    int t2 = t - 10; int p = t2 / 2, k = t2 % 2;
    const float* w1R = p ? wY1R : wX1R;
    int off = p ? F : 0;
    float s = 0.f;
    for (int f = 0; f < F; ++f) s += wfc[off + f] * w1R[f * 2 + k];
    r1Rs[p][k] = s;
  } else if (t < 14 + 96) {          // second-order interior: 2 x 16fi x 3
    int t2 = t - 14; int p = t2 / 48; int r = t2 % 48; int fi = r / 3, k = r % 3;
    const float* w2 = p ? wY2 : wX2;
    int off = p ? 3 * F : 2 * F;
    float s = 0.f;
    for (int fo = 0; fo < F; ++fo) s += wfc[off + fo] * w2[(fo * F + fi) * 3 + k];
    qs[p][fi][k] = s;
  } else if (t < 110 + 64) {         // second-order left boundary
    int t2 = t - 110; int p = t2 / 32; int r = t2 % 32; int fi = r / 2, k = r % 2;
    const float* w2L = p ? wY2L : wX2L;
    int off = p ? 3 * F : 2 * F;
    float s = 0.f;
    for (int fo = 0; fo < F; ++fo) s += wfc[off + fo] * w2L[(fo * F + fi) * 2 + k];
    qLs[p][fi][k] = s;
  } else if (t < 174 + 64) {         // second-order right boundary
    int t2 = t - 174; int p = t2 / 32; int r = t2 % 32; int fi = r / 2, k = r % 2;
    const float* w2R = p ? wY2R : wX2R;
    int off = p ? 3 * F : 2 * F;
    float s = 0.f;
    for (int fo = 0; fo < F; ++fo) s += wfc[off + fo] * w2R[(fo * F + fi) * 2 + k];
    qRs[p][fi][k] = s;
  }
  __syncthreads();

  int gid = blockIdx.x * 256 + t;
  if (gid >= 2 * XL * 5) return;
  const int p = gid / (XL * 5);
  const int rem = gid % (XL * 5);
  const int w = rem / 5;
  const int d = rem % 5;
  const int wp = w + d - 2;

  const float* w1  = p ? wY1  : wX1;
  const float* w1L = p ? wY1L : wX1L;
  const float* w1R = p ? wY1R : wX1R;

  float c = 0.f;
  if (wp >= 0 && wp < XL) {
    // first-order contribution
    if (w == 0) {
      if (wp == 0)       c += r1Ls[p][0];
      else if (wp == 1)  c += r1Ls[p][1];
    } else if (w == XL - 1) {
      if (wp == XL - 2)      c += r1Rs[p][0];
      else if (wp == XL - 1) c += r1Rs[p][1];
    } else {
      int k = wp - (w - 1);
      if (k >= 0 && k < 3) c += r1s[p][k];
    }
    // second-order contribution
    if (w == 0) {
      for (int vi = 0; vi < 2; ++vi)
        for (int fi = 0; fi < F; ++fi)
          c += qLs[p][fi][vi] * g1f(w1, w1L, w1R, fi, vi, wp);
    } else if (w == XL - 1) {
      for (int vi = 0; vi < 2; ++vi)
        for (int fi = 0; fi < F; ++fi)
          c += qRs[p][fi][vi] * g1f(w1, w1L, w1R, fi, XL - 2 + vi, wp);
    } else {
      for (int k2 = 0; k2 < 3; ++k2) {
        int v = w - 1 + k2;
        for (int fi = 0; fi < F; ++fi)
          c += qs[p][fi][k2] * g1f(w1, w1L, w1R, fi, v, wp);
      }
    }
  }
  bands[(p * 5 + d) * XL + w] = c;
}

// 256 blocks = 64 images x 4 strips. Each block: 64-row strip, double-buffered
// in LDS (2 x 32 KB). 8 iterations done locally (trapezoidal time tiling,
// halo 16 = 8 iters x radius 2). Each thread owns a column PAIR (float2/b64
// LDS traffic) x 16 rows. Final iteration streams straight to global.
__global__ __launch_bounds__(256)
void fd_main_kernel(const float* __restrict__ x_in, const float* __restrict__ bands,
                    const int* __restrict__ fdp, float* __restrict__ x_out) {
  __shared__ float buf[2][64 * XL];   // 64 KB double buffer
  __shared__ float cbl[5 * XL];       // column band table (boundary rows)

  const int tid = threadIdx.x;
  const int n = blockIdx.x >> 2;
  const int s = blockIdx.x & 3;
  const int g0 = (s == 0) ? 0 : (s == 1) ? 16 : (s == 2) ? 48 : 64;  // first global row in buffer
  const int l0 = (s == 0) ? 0 : (s == 3) ? 32 : 16;                  // local row of first interior row

  if (tid < XL) {
#pragma unroll
    for (int d = 0; d < 5; ++d) cbl[d * XL + tid] = bands[(5 + d) * XL + tid];
  }

  // load strip rows [g0, g0+64) into buf[0]
  {
    const float4* sg4 = (const float4*)(x_in + n * (XL * XL) + g0 * XL);
    float4* b4 = (float4*)buf[0];
#pragma unroll
    for (int i = 0; i < 8; ++i) b4[tid + 256 * i] = sg4[tid + 256 * i];
  }

  const int p = tid & 63;       // column pair: cols 2p, 2p+1
  const int rg = tid >> 6;      // row group 0..3 (wave-uniform)
  const int rbase = rg << 4;    // rows [rbase, rbase+16)
  const int pm = (p > 0) ? p - 1 : 0;
  const int pp = (p < 63) ? p + 1 : 63;

  // row-band coefficients for this thread's two columns (OOB taps are 0,
  // so clamped-index garbage reads are multiplied by zero)
  const float2* bp2 = (const float2*)bands;   // [d][64 pairs]
  const float2 rb0 = bp2[0 * 64 + p];
  const float2 rb1 = bp2[1 * 64 + p];
  const float2 rb2 = bp2[2 * 64 + p];
  const float2 rb3 = bp2[3 * 64 + p];
  const float2 rb4 = bp2[4 * 64 + p];
  // interior column-band coefficients (position-independent for rows 2..125)
  const float cbi0 = bands[(5 + 0) * XL + 64];
  const float cbi1 = bands[(5 + 1) * XL + 64];
  const float cbi2 = bands[(5 + 2) * XL + 64];
  const float cbi3 = bands[(5 + 3) * XL + 64];
  const float cbi4 = bands[(5 + 4) * XL + 64];

  const int fdb = fdp[0];
  float2* out2 = (float2*)(x_out + n * (XL * XL));

  __syncthreads();

  if (fdb == 0) {   // copy-through
    const float2* bc = (const float2*)buf[0];
#pragma unroll
    for (int j = 0; j < 16; ++j) {
      const int r = rbase + j;
      const int lr = r - l0;
      if (lr >= 0 && lr < 32) out2[(32 * s + lr) * 64 + p] = bc[r * 64 + p];
    }
    return;
  }

  for (int t = 0; t < fdb; ++t) {
    const float2* bc = (const float2*)buf[t & 1];
    float2* bn = (float2*)buf[(t & 1) ^ 1];
    const bool last = (t == fdb - 1);

    // rolling vertical window: rows r-2 .. r+2, this thread's column pair
    float2 c_m2 = bc[((rbase >= 2) ? rbase - 2 : 0) * 64 + p];
    float2 c_m1 = bc[((rbase >= 1) ? rbase - 1 : 0) * 64 + p];
    float2 c_0  = bc[(rbase + 0) * 64 + p];
    float2 c_p1 = bc[(rbase + 1) * 64 + p];
    float2 c_p2 = bc[(rbase + 2) * 64 + p];

#pragma unroll
    for (int j = 0; j < 16; ++j) {
      const int r = rbase + j;
      const int gh = g0 + r;
      const float2 hl = bc[r * 64 + pm];   // cols w0-2, w0-1
      const float2 hr = bc[r * 64 + pp];   // cols w1+1, w1+2
      float b0 = cbi0, b1 = cbi1, b2 = cbi2, b3 = cbi3, b4 = cbi4;
      if (gh < 2 || gh > 125) {   // wave-uniform branch, 4 rows per image
        b0 = cbl[0 * XL + gh]; b1 = cbl[1 * XL + gh]; b2 = cbl[2 * XL + gh];
        b3 = cbl[3 * XL + gh]; b4 = cbl[4 * XL + gh];
      }
      // col w0 = 2p: neighbors hl.x, hl.y, [c_0.x], c_0.y, hr.x
      float a0 = c_0.x
        + rb0.x * hl.x  + rb1.x * hl.y  + rb2.x * c_0.x + rb3.x * c_0.y + rb4.x * hr.x
        + b0 * c_m2.x + b1 * c_m1.x + b2 * c_0.x + b3 * c_p1.x + b4 * c_p2.x;
      // col w1 = 2p+1: neighbors hl.y, c_0.x, [c_0.y], hr.x, hr.y
      float a1 = c_0.y
        + rb0.y * hl.y  + rb1.y * c_0.x + rb2.y * c_0.y + rb3.y * hr.x  + rb4.y * hr.y
        + b0 * c_m2.y + b1 * c_m1.y + b2 * c_0.y + b3 * c_p1.y + b4 * c_p2.y;

      if (!last) {
        bn[r * 64 + p] = make_float2(a0, a1);
      } else {
        const int lr = r - l0;
        if (lr >= 0 && lr < 32) out2[(32 * s + lr) * 64 + p] = make_float2(a0, a1);
      }
      // roll window down one row
      c_m2 = c_m1; c_m1 = c_0; c_0 = c_p1; c_p1 = c_p2;
      const int rn = (r + 3 <= 63) ? r + 3 : 63;
      c_p2 = bc[rn * 64 + p];
    }
    if (!last) __syncthreads();
  }
}

extern "C" void kernel_launch(void* const* d_in, const int* in_sizes, int n_in,
                              void* d_out, int out_size, void* d_ws, size_t ws_size,
                              hipStream_t stream) {
  const float* xInput = (const float*)d_in[0];
  const float* wX1  = (const float*)d_in[1];
  const float* wX1L = (const float*)d_in[2];
  const float* wX1R = (const float*)d_in[3];
  const float* wY1  = (const float*)d_in[4];
  const float* wY1L = (const float*)d_in[5];
  const float* wY1R = (const float*)d_in[6];
  const float* wX2  = (const float*)d_in[7];
  const float* wX2L = (const float*)d_in[8];
  const float* wX2R = (const float*)d_in[9];
  const float* wY2  = (const float*)d_in[10];
  const float* wY2L = (const float*)d_in[11];
  const float* wY2R = (const float*)d_in[12];
  const float* wfc  = (const float*)d_in[13];
  const int*   fdp  = (const int*)d_in[14];

  float* bands = (float*)d_ws;           // 2*5*128 floats = 5120 B
  float* out = (float*)d_out;

  build_bands_kernel<<<5, 256, 0, stream>>>(wX1, wX1L, wX1R, wY1, wY1L, wY1R,
                                            wX2, wX2L, wX2R, wY2, wY2L, wY2R,
                                            wfc, bands);
  fd_main_kernel<<<256, 256, 0, stream>>>(xInput, bands, fdp, out);
}

// Round 3
// 108.656 us; speedup vs baseline: 1.2001x; 1.0136x over previous
//
#include <hip/hip_runtime.h>

#define F 16
#define XL 128

// Band operators: bands[p][d][pos] = coefficient of u[pos + d - 2] in the
// deviation at pos; p=0 row (x/w) operator, p=1 column (y/h) operator.
// Out-of-range taps are stored as 0, so clamped-index garbage reads are
// annihilated by multiplication.

__device__ __forceinline__ float g1f(const float* __restrict__ w1,
                                     const float* __restrict__ w1L,
                                     const float* __restrict__ w1R,
                                     int f, int v, int wp) {
  // coefficient of u[wp] in first-order field dX[f, v]
  if (v == 0) {
    if (wp == 0) return w1L[f * 2 + 0];
    if (wp == 1) return w1L[f * 2 + 1];
    return 0.f;
  }
  if (v == XL - 1) {
    if (wp == XL - 2) return w1R[f * 2 + 0];
    if (wp == XL - 1) return w1R[f * 2 + 1];
    return 0.f;
  }
  int k = wp - (v - 1);
  return (k >= 0 && k < 3) ? w1[f * 3 + k] : 0.f;
}

// Single fused kernel. 256 blocks = 64 images x 4 strips, 512 threads
// (8 waves/CU = 2 waves/SIMD). Per block: band-table preamble in LDS,
// then 64-row strip (32 interior + 16-row halos = 8 iters x radius 2)
// double-buffered in LDS, all 8 iterations local (trapezoidal time tiling).
// Each thread owns 4 cols x 4 rows (b128 LDS traffic). Final iteration
// streams straight to global.
__global__ __launch_bounds__(512)
void fd_fused_kernel(const float* __restrict__ x_in,
                     const float* __restrict__ wX1, const float* __restrict__ wX1L,
                     const float* __restrict__ wX1R, const float* __restrict__ wY1,
                     const float* __restrict__ wY1L, const float* __restrict__ wY1R,
                     const float* __restrict__ wX2, const float* __restrict__ wX2L,
                     const float* __restrict__ wX2R, const float* __restrict__ wY2,
                     const float* __restrict__ wY2L, const float* __restrict__ wY2R,
                     const float* __restrict__ wfc, const int* __restrict__ fdp,
                     float* __restrict__ x_out) {
  __shared__ __align__(16) float buf[2][64 * XL];   // 64 KB double buffer
  __shared__ __align__(16) float rbl[5][XL];        // row-band table
  __shared__ __align__(16) float cbl[5][XL];        // col-band table
  __shared__ float r1s[2][3], r1Ls[2][2], r1Rs[2][2];
  __shared__ float qs[2][F][3], qLs[2][F][2], qRs[2][F][2];

  const int tid = threadIdx.x;
  const int n = blockIdx.x >> 2;
  const int s = blockIdx.x & 3;
  const int g0 = (s == 0) ? 0 : (s == 1) ? 16 : (s == 2) ? 48 : 64;  // first global row in buffer
  const int l0 = (s == 0) ? 0 : (s == 3) ? 32 : 16;                  // local row of first interior row

  // stage strip rows [g0, g0+64) into buf[0] (2048 float4 / 512 threads)
  {
    const float4* sg4 = (const float4*)(x_in + n * (XL * XL) + g0 * XL);
    float4* b4 = (float4*)buf[0];
#pragma unroll
    for (int i = 0; i < 4; ++i) b4[tid + 512 * i] = sg4[tid + 512 * i];
  }

  // ---- preamble phase 1: fc-reduced weights ----
  {
    const int t = tid;
    if (t < 6) {                       // first-order interior: 2 passes x 3 taps
      int p = t / 3, k = t % 3;
      const float* w1 = p ? wY1 : wX1;
      int off = p ? F : 0;
      float sm = 0.f;
      for (int f = 0; f < F; ++f) sm += wfc[off + f] * w1[f * 3 + k];
      r1s[p][k] = sm;
    } else if (t < 10) {               // first-order left boundary
      int t2 = t - 6; int p = t2 / 2, k = t2 % 2;
      const float* w1L = p ? wY1L : wX1L;
      int off = p ? F : 0;
      float sm = 0.f;
      for (int f = 0; f < F; ++f) sm += wfc[off + f] * w1L[f * 2 + k];
      r1Ls[p][k] = sm;
    } else if (t < 14) {               // first-order right boundary
      int t2 = t - 10; int p = t2 / 2, k = t2 % 2;
      const float* w1R = p ? wY1R : wX1R;
      int off = p ? F : 0;
      float sm = 0.f;
      for (int f = 0; f < F; ++f) sm += wfc[off + f] * w1R[f * 2 + k];
      r1Rs[p][k] = sm;
    } else if (t < 14 + 96) {          // second-order interior: 2 x 16fi x 3
      int t2 = t - 14; int p = t2 / 48; int r = t2 % 48; int fi = r / 3, k = r % 3;
      const float* w2 = p ? wY2 : wX2;
      int off = p ? 3 * F : 2 * F;
      float sm = 0.f;
      for (int fo = 0; fo < F; ++fo) sm += wfc[off + fo] * w2[(fo * F + fi) * 3 + k];
      qs[p][fi][k] = sm;
    } else if (t < 110 + 64) {         // second-order left boundary
      int t2 = t - 110; int p = t2 / 32; int r = t2 % 32; int fi = r / 2, k = r % 2;
      const float* w2L = p ? wY2L : wX2L;
      int off = p ? 3 * F : 2 * F;
      float sm = 0.f;
      for (int fo = 0; fo < F; ++fo) sm += wfc[off + fo] * w2L[(fo * F + fi) * 2 + k];
      qLs[p][fi][k] = sm;
    } else if (t < 174 + 64) {         // second-order right boundary
      int t2 = t - 174; int p = t2 / 32; int r = t2 % 32; int fi = r / 2, k = r % 2;
      const float* w2R = p ? wY2R : wX2R;
      int off = p ? 3 * F : 2 * F;
      float sm = 0.f;
      for (int fo = 0; fo < F; ++fo) sm += wfc[off + fo] * w2R[(fo * F + fi) * 2 + k];
      qRs[p][fi][k] = sm;
    }
  }
  __syncthreads();

  // ---- preamble phase 2: compose 5-tap band tables ----
  for (int e = tid; e < 2 * 5 * XL; e += 512) {
    const int pp = e / (5 * XL);
    const int rem = e % (5 * XL);
    const int w = rem / 5;
    const int d = rem % 5;
    const int wp = w + d - 2;
    const float* w1  = pp ? wY1  : wX1;
    const float* w1L = pp ? wY1L : wX1L;
    const float* w1R = pp ? wY1R : wX1R;
    float c = 0.f;
    if (wp >= 0 && wp < XL) {
      // first-order contribution
      if (w == 0) {
        if (wp == 0)       c += r1Ls[pp][0];
        else if (wp == 1)  c += r1Ls[pp][1];
      } else if (w == XL - 1) {
        if (wp == XL - 2)      c += r1Rs[pp][0];
        else if (wp == XL - 1) c += r1Rs[pp][1];
      } else {
        int k = wp - (w - 1);
        if (k >= 0 && k < 3) c += r1s[pp][k];
      }
      // second-order contribution
      if (w == 0) {
        for (int vi = 0; vi < 2; ++vi)
          for (int fi = 0; fi < F; ++fi)
            c += qLs[pp][fi][vi] * g1f(w1, w1L, w1R, fi, vi, wp);
      } else if (w == XL - 1) {
        for (int vi = 0; vi < 2; ++vi)
          for (int fi = 0; fi < F; ++fi)
            c += qRs[pp][fi][vi] * g1f(w1, w1L, w1R, fi, XL - 2 + vi, wp);
      } else {
        for (int k2 = 0; k2 < 3; ++k2) {
          int v = w - 1 + k2;
          for (int fi = 0; fi < F; ++fi)
            c += qs[pp][fi][k2] * g1f(w1, w1L, w1R, fi, v, wp);
        }
      }
    }
    if (pp == 0) rbl[d][w] = c; else cbl[d][w] = c;
  }
  __syncthreads();   // covers buf[0] staging + band tables

  // ---- main time-stepping loop ----
  const int q = tid & 31;              // column quad: cols 4q..4q+3
  const int rbase = (tid >> 5) << 2;   // rows [rbase, rbase+4)
  const int plm = (q > 0) ? 2 * q - 1 : 0;    // left halo pair (cols 4q-2,4q-1)
  const int prm = (q < 31) ? 2 * q + 2 : 63;  // right halo pair (cols 4q+4,4q+5)

  // row-band coefficients for this thread's 4 columns
  const float4 rb0 = ((const float4*)rbl[0])[q];
  const float4 rb1 = ((const float4*)rbl[1])[q];
  const float4 rb2 = ((const float4*)rbl[2])[q];
  const float4 rb3 = ((const float4*)rbl[3])[q];
  const float4 rb4 = ((const float4*)rbl[4])[q];
  // interior column-band coefficients (position-independent for rows 2..125)
  const float cbi0 = cbl[0][64];
  const float cbi1 = cbl[1][64];
  const float cbi2 = cbl[2][64];
  const float cbi3 = cbl[3][64];
  const float cbi4 = cbl[4][64];

  const int fdb = fdp[0];
  float4* out4 = (float4*)(x_out + n * (XL * XL));

  if (fdb == 0) {   // copy-through
    const float4* bc = (const float4*)buf[0];
#pragma unroll
    for (int j = 0; j < 4; ++j) {
      const int r = rbase + j;
      const int lr = r - l0;
      if (lr >= 0 && lr < 32) out4[(32 * s + lr) * 32 + q] = bc[r * 32 + q];
    }
    return;
  }

  for (int t = 0; t < fdb; ++t) {
    const float4* bc  = (const float4*)buf[t & 1];
    const float2* bc2 = (const float2*)buf[t & 1];
    float4* bn = (float4*)buf[(t & 1) ^ 1];
    const bool last = (t == fdb - 1);

    // rolling vertical window: rows r-2..r+2, this thread's 4 columns
    float4 c_m2 = bc[((rbase >= 2) ? rbase - 2 : 0) * 32 + q];
    float4 c_m1 = bc[((rbase >= 1) ? rbase - 1 : 0) * 32 + q];
    float4 c_0  = bc[(rbase + 0) * 32 + q];
    float4 c_p1 = bc[(rbase + 1) * 32 + q];
    float4 c_p2 = bc[(rbase + 2) * 32 + q];

#pragma unroll
    for (int j = 0; j < 4; ++j) {
      const int r = rbase + j;
      const int gh = g0 + r;
      const float2 hl = bc2[r * 64 + plm];   // cols 4q-2, 4q-1
      const float2 hr = bc2[r * 64 + prm];   // cols 4q+4, 4q+5
      float b0 = cbi0, b1 = cbi1, b2 = cbi2, b3 = cbi3, b4c = cbi4;
      if (gh < 2 || gh > 125) {              // 4 rows per image
        b0 = cbl[0][gh]; b1 = cbl[1][gh]; b2 = cbl[2][gh];
        b3 = cbl[3][gh]; b4c = cbl[4][gh];
      }
      float4 a;
      a.x = c_0.x
        + rb0.x * hl.x  + rb1.x * hl.y  + rb2.x * c_0.x + rb3.x * c_0.y + rb4.x * c_0.z
        + b0 * c_m2.x + b1 * c_m1.x + b2 * c_0.x + b3 * c_p1.x + b4c * c_p2.x;
      a.y = c_0.y
        + rb0.y * hl.y  + rb1.y * c_0.x + rb2.y * c_0.y + rb3.y * c_0.z + rb4.y * c_0.w
        + b0 * c_m2.y + b1 * c_m1.y + b2 * c_0.y + b3 * c_p1.y + b4c * c_p2.y;
      a.z = c_0.z
        + rb0.z * c_0.x + rb1.z * c_0.y + rb2.z * c_0.z + rb3.z * c_0.w + rb4.z * hr.x
        + b0 * c_m2.z + b1 * c_m1.z + b2 * c_0.z + b3 * c_p1.z + b4c * c_p2.z;
      a.w = c_0.w
        + rb0.w * c_0.y + rb1.w * c_0.z + rb2.w * c_0.w + rb3.w * hr.x  + rb4.w * hr.y
        + b0 * c_m2.w + b1 * c_m1.w + b2 * c_0.w + b3 * c_p1.w + b4c * c_p2.w;

      if (!last) {
        bn[r * 32 + q] = a;
      } else {
        const int lr = r - l0;
        if (lr >= 0 && lr < 32) out4[(32 * s + lr) * 32 + q] = a;
      }
      // roll window down one row
      c_m2 = c_m1; c_m1 = c_0; c_0 = c_p1; c_p1 = c_p2;
      const int rn = (r + 3 <= 63) ? r + 3 : 63;
      c_p2 = bc[rn * 32 + q];
    }
    if (!last) __syncthreads();
  }
}

extern "C" void kernel_launch(void* const* d_in, const int* in_sizes, int n_in,
                              void* d_out, int out_size, void* d_ws, size_t ws_size,
                              hipStream_t stream) {
  const float* xInput = (const float*)d_in[0];
  const float* wX1  = (const float*)d_in[1];
  const float* wX1L = (const float*)d_in[2];
  const float* wX1R = (const float*)d_in[3];
  const float* wY1  = (const float*)d_in[4];
  const float* wY1L = (const float*)d_in[5];
  const float* wY1R = (const float*)d_in[6];
  const float* wX2  = (const float*)d_in[7];
  const float* wX2L = (const float*)d_in[8];
  const float* wX2R = (const float*)d_in[9];
  const float* wY2  = (const float*)d_in[10];
  const float* wY2L = (const float*)d_in[11];
  const float* wY2R = (const float*)d_in[12];
  const float* wfc  = (const float*)d_in[13];
  const int*   fdp  = (const int*)d_in[14];

  float* out = (float*)d_out;

  fd_fused_kernel<<<256, 512, 0, stream>>>(xInput, wX1, wX1L, wX1R, wY1, wY1L, wY1R,
                                           wX2, wX2L, wX2R, wY2, wY2L, wY2R,
                                           wfc, fdp, out);
}